// Round 3
// baseline (448.417 us; speedup 1.0000x reference)
//
#include <hip/hip_runtime.h>

// VQ-VAE vector quantizer. Round 3: fp16 MFMA scoring + exact-fp32 margin rescue.
// z: [16,64,32,32] f32, emb: [8192,64] f32. N=16384 pts, C=64, V=8192.
// out = [ z_q_st (1048576) | idx as f32 (16384) | vq_loss (1) ]
//
// score(n,v) = z_n.e_v - 0.5*||e_v||^2  (argmax score == argmin dist)
// k1: v_mfma_f32_32x32x16_f16, per-row top-2 tracked; fp16 score error
// sigma~0.004. k2 merges 8 v-splits; margin < THR=0.08 (~10 sigma) -> rescue
// list; k_rescue recomputes those points exactly in fp32 over all codes.

typedef _Float16 half8 __attribute__((ext_vector_type(8)));
typedef float f32x16 __attribute__((ext_vector_type(16)));
typedef unsigned short ushortx8 __attribute__((ext_vector_type(8)));

#define N_PTS 16384
#define SPLITS 8
#define THR 0.08f

// ---------------- k_pre: emb -> fp16, half-norms, zero counters ----------------
__global__ __launch_bounds__(256) void k_pre(const float* __restrict__ emb,
                                             float* __restrict__ h,
                                             unsigned short* __restrict__ e16,
                                             int* __restrict__ cnt) {
  int v = blockIdx.x * 256 + threadIdx.x;   // grid 32 -> 8192
  const float4* e4 = (const float4*)(emb + v * 64);
  float s = 0.f;
#pragma unroll
  for (int i = 0; i < 8; ++i) {
    float4 a = e4[2 * i], b = e4[2 * i + 1];
    s += a.x * a.x + a.y * a.y + a.z * a.z + a.w * a.w;
    s += b.x * b.x + b.y * b.y + b.z * b.z + b.w * b.w;
    half8 o;
    o[0] = (_Float16)a.x; o[1] = (_Float16)a.y; o[2] = (_Float16)a.z; o[3] = (_Float16)a.w;
    o[4] = (_Float16)b.x; o[5] = (_Float16)b.y; o[6] = (_Float16)b.z; o[7] = (_Float16)b.w;
    *(half8*)(e16 + v * 64 + i * 8) = o;
  }
  h[v] = 0.5f * s;
  if (v == 0) *cnt = 0;
}

// ---------------- k1: MFMA scores + per-split top-2 ----------------
// grid (64, 8). block 256 = 4 waves; wave owns 64 points (2 subtiles of 32),
// block owns 256 points and sweeps 1024 codes (8 chunks of 128 = 4 v-tiles).
__global__ __launch_bounds__(256, 2) void k1_score(
    const float* __restrict__ z, const unsigned short* __restrict__ e16,
    const float* __restrict__ h,
    float* __restrict__ ps, float* __restrict__ pi, float* __restrict__ p2) {
  __shared__ unsigned short es[128 * 72];   // 128 codes x 64 halfs, pad 72 (16B rows)
  __shared__ float h_s[128];

  const int tid = threadIdx.x;
  const int lane = tid & 63;
  const int wid = tid >> 6;
  const int h5 = lane >> 5;     // k-half
  const int c5 = lane & 31;     // col (code) / row (point) id within 32
  const int n0 = blockIdx.x * 256;
  const int split = blockIdx.y;

  const int b = n0 >> 10;
  const int hw0 = n0 & 1023;

  // A fragments: A[m=c5][k=h5*8+j], k = channel. Loaded once, fp32->fp16.
  half8 A[2][4];
  {
    const float* zb = z + b * 65536 + hw0 + wid * 64 + c5;
#pragma unroll
    for (int sub = 0; sub < 2; ++sub)
#pragma unroll
      for (int kc = 0; kc < 4; ++kc) {
        half8 a;
#pragma unroll
        for (int j = 0; j < 8; ++j)
          a[j] = (_Float16)zb[sub * 32 + (kc * 16 + h5 * 8 + j) * 1024];
        A[sub][kc] = a;
      }
  }

  float s1[2][16], i1[2][16], s2[2][16];
#pragma unroll
  for (int sub = 0; sub < 2; ++sub)
#pragma unroll
    for (int e = 0; e < 16; ++e) {
      s1[sub][e] = -3.0e38f; i1[sub][e] = 0.f; s2[sub][e] = -3.0e38f;
    }

  for (int ch = 0; ch < 8; ++ch) {
    const int vb = split * 1024 + ch * 128;
    __syncthreads();
    {
      const unsigned short* src = e16 + vb * 64;
#pragma unroll
      for (int q = 0; q < 4; ++q) {
        int f = q * 2048 + tid * 8;       // f = code*64 + c
        int r = f >> 6, c = f & 63;
        ushortx8 val = *(const ushortx8*)(src + f);
        *(ushortx8*)&es[r * 72 + c] = val;
      }
      if (tid < 128) h_s[tid] = h[vb + tid];
    }
    __syncthreads();

#pragma unroll
    for (int t = 0; t < 4; ++t) {
      // B fragments: B[n=c5][k=h5*8+j]
      half8 B[4];
      const int rr = t * 32 + c5;
#pragma unroll
      for (int kc = 0; kc < 4; ++kc)
        B[kc] = *(const half8*)&es[rr * 72 + kc * 16 + h5 * 8];
      const float hv = h_s[rr];
      const float vf = (float)(vb + rr);
      const float nhv = -hv;

#pragma unroll
      for (int sub = 0; sub < 2; ++sub) {
        f32x16 acc;
#pragma unroll
        for (int e = 0; e < 16; ++e) acc[e] = nhv;
#pragma unroll
        for (int kc = 0; kc < 4; ++kc)
          acc = __builtin_amdgcn_mfma_f32_32x32x16_f16(A[sub][kc], B[kc], acc, 0, 0, 0);
#pragma unroll
        for (int e = 0; e < 16; ++e) {
          float sc = acc[e];
          float mn = fminf(sc, s1[sub][e]);
          bool gt = sc > s1[sub][e];
          s2[sub][e] = fmaxf(s2[sub][e], mn);
          i1[sub][e] = gt ? vf : i1[sub][e];
          s1[sub][e] = fmaxf(s1[sub][e], sc);
        }
      }
    }
  }

  // butterfly merge across the 32 col-lanes (ties resolved by rescue)
#pragma unroll
  for (int off = 16; off >= 1; off >>= 1) {
#pragma unroll
    for (int sub = 0; sub < 2; ++sub)
#pragma unroll
      for (int e = 0; e < 16; ++e) {
        float os = __shfl_xor(s1[sub][e], off);
        float oi = __shfl_xor(i1[sub][e], off);
        float o2 = __shfl_xor(s2[sub][e], off);
        float mn = fminf(s1[sub][e], os);
        s2[sub][e] = fmaxf(fmaxf(s2[sub][e], o2), mn);
        bool gt = os > s1[sub][e];
        i1[sub][e] = gt ? oi : i1[sub][e];
        s1[sub][e] = fmaxf(s1[sub][e], os);
      }
  }

  if (c5 == 0) {
#pragma unroll
    for (int sub = 0; sub < 2; ++sub)
#pragma unroll
      for (int e = 0; e < 16; ++e) {
        int n = n0 + wid * 64 + sub * 32 + (e & 3) + 8 * (e >> 2) + 4 * h5;
        int o = split * N_PTS + n;
        ps[o] = s1[sub][e]; pi[o] = i1[sub][e]; p2[o] = s2[sub][e];
      }
  }
}

// ---------------- k2: merge splits, margin test, emit idx ----------------
__global__ __launch_bounds__(256) void k2_merge(
    const float* __restrict__ ps, const float* __restrict__ pi,
    const float* __restrict__ p2,
    int* __restrict__ idxf, float* __restrict__ out_idx,
    int* __restrict__ list, int* __restrict__ cnt, float* __restrict__ acc) {
  int n = blockIdx.x * 256 + threadIdx.x;   // grid 64 -> 16384
  float S1 = ps[n], I1 = pi[n], S2 = p2[n];
#pragma unroll
  for (int s = 1; s < SPLITS; ++s) {
    int o = s * N_PTS + n;
    float a = ps[o], ai = pi[o], a2 = p2[o];
    if (a > S1) { S2 = fmaxf(fmaxf(S2, a2), S1); S1 = a; I1 = ai; }
    else        { S2 = fmaxf(S2, a); }
  }
  idxf[n] = (int)I1;
  out_idx[n] = I1;
  if (S1 - S2 < THR) {
    int p = atomicAdd(cnt, 1);
    list[p] = n;
  }
  if (n == 0) *acc = 0.f;
}

// ---------------- k_rescue: exact fp32 recompute for ambiguous points ----------
__global__ __launch_bounds__(512) void k_rescue(
    const float* __restrict__ z, const float* __restrict__ emb,
    const float* __restrict__ h, const int* __restrict__ list,
    const int* __restrict__ cnt,
    int* __restrict__ idxf, float* __restrict__ out_idx) {
  __shared__ float zs[4][64];
  __shared__ int pn[4];
  __shared__ float rs[8][4], ri[8][4];
  const int tid = threadIdx.x;
  const int lane = tid & 63, wv = tid >> 6;
  const int count = *cnt;

  for (int base = blockIdx.x * 4; base < count; base += 128 * 4) {
    const int P = min(4, count - base);
    __syncthreads();
    if (tid < P) pn[tid] = list[base + tid];
    __syncthreads();
    if (tid < P * 16) {
      int p = tid >> 4, i = tid & 15;
      int n = pn[p], bb = n >> 10, hw = n & 1023;
      float4 v;
      v.x = z[bb * 65536 + (i * 4 + 0) * 1024 + hw];
      v.y = z[bb * 65536 + (i * 4 + 1) * 1024 + hw];
      v.z = z[bb * 65536 + (i * 4 + 2) * 1024 + hw];
      v.w = z[bb * 65536 + (i * 4 + 3) * 1024 + hw];
      *(float4*)&zs[p][i * 4] = v;
    }
    __syncthreads();

    float bs[4], bi[4];
#pragma unroll
    for (int p = 0; p < 4; ++p) { bs[p] = -3.0e38f; bi[p] = 0.f; }

    for (int q = 0; q < 16; ++q) {
      int v = q * 512 + tid;
      const float4* er = (const float4*)(emb + v * 64);
      float d[4] = {0.f, 0.f, 0.f, 0.f};
#pragma unroll
      for (int i = 0; i < 16; ++i) {
        float4 ev = er[i];
#pragma unroll
        for (int p = 0; p < 4; ++p) {
          d[p] = fmaf(ev.x, zs[p][i * 4 + 0], d[p]);
          d[p] = fmaf(ev.y, zs[p][i * 4 + 1], d[p]);
          d[p] = fmaf(ev.z, zs[p][i * 4 + 2], d[p]);
          d[p] = fmaf(ev.w, zs[p][i * 4 + 3], d[p]);
        }
      }
      float hv = h[v];
#pragma unroll
      for (int p = 0; p < 4; ++p) {
        float sc = d[p] - hv;
        if (sc > bs[p]) { bs[p] = sc; bi[p] = (float)v; }
      }
    }

    // wave butterfly with index tie-break (lower v wins)
#pragma unroll
    for (int off = 32; off >= 1; off >>= 1)
#pragma unroll
      for (int p = 0; p < 4; ++p) {
        float os = __shfl_xor(bs[p], off);
        float oi = __shfl_xor(bi[p], off);
        if (os > bs[p] || (os == bs[p] && oi < bi[p])) { bs[p] = os; bi[p] = oi; }
      }
    if (lane == 0)
#pragma unroll
      for (int p = 0; p < 4; ++p) { rs[wv][p] = bs[p]; ri[wv][p] = bi[p]; }
    __syncthreads();
    if (tid < 4) {
      int p = tid;
      float s = rs[0][p], i = ri[0][p];
#pragma unroll
      for (int w = 1; w < 8; ++w) {
        float os = rs[w][p], oi = ri[w][p];
        if (os > s || (os == s && oi < i)) { s = os; i = oi; }
      }
      if (p < P) {
        int n = pn[p];
        idxf[n] = (int)i;
        out_idx[n] = i;
      }
    }
  }
}

// ---------------- k3: gather, straight-through out, loss partial ----------------
__global__ __launch_bounds__(256) void k3_quant(
    const float* __restrict__ z, const float* __restrict__ emb,
    const int* __restrict__ idxf,
    float* __restrict__ out, float* __restrict__ acc) {
  int g = blockIdx.x * 256 + threadIdx.x;   // grid 4096 -> 1048576, [b][c][hw]
  int b = g >> 16;
  int c = (g >> 10) & 63;
  int hw = g & 1023;
  int n = (b << 10) | hw;
  float zv = z[g];
  float q = emb[idxf[n] * 64 + c];
  float d = q - zv;
  out[g] = zv + d;
  float val = d * d;
#pragma unroll
  for (int off = 32; off >= 1; off >>= 1) val += __shfl_down(val, off);
  __shared__ float wsum[4];
  int lane = threadIdx.x & 63, wv = threadIdx.x >> 6;
  if (lane == 0) wsum[wv] = val;
  __syncthreads();
  if (threadIdx.x == 0)
    atomicAdd(acc, wsum[0] + wsum[1] + wsum[2] + wsum[3]);
}

// ---------------- k4: finalize loss ----------------
__global__ void k4_loss(const float* __restrict__ acc, float* __restrict__ out_loss) {
  out_loss[0] = 1.25f * acc[0] * (1.0f / 1048576.0f);
}

extern "C" void kernel_launch(void* const* d_in, const int* in_sizes, int n_in,
                              void* d_out, int out_size, void* d_ws, size_t ws_size,
                              hipStream_t stream) {
  const float* z   = (const float*)d_in[0];
  const float* emb = (const float*)d_in[1];
  float* out = (float*)d_out;
  float* ws  = (float*)d_ws;

  // ws layout (floats):
  float* h   = ws;                                   // 8192
  unsigned short* e16 = (unsigned short*)(ws + 8192); // 524288 halfs = 262144 f
  float* ps  = ws + 8192 + 262144;                   // 8*16384
  float* pi  = ps + SPLITS * N_PTS;                  // 8*16384
  float* p2  = pi + SPLITS * N_PTS;                  // 8*16384
  int* idxf  = (int*)(p2 + SPLITS * N_PTS);          // 16384
  int* list  = idxf + N_PTS;                         // 16384
  int* cnt   = list + N_PTS;                         // 1
  float* acc = (float*)(cnt + 1);                    // 1

  float* out_zq   = out;
  float* out_idx  = out + 1048576;
  float* out_loss = out + 1048576 + 16384;
  (void)out_zq;

  k_pre<<<32, 256, 0, stream>>>(emb, h, e16, cnt);
  k1_score<<<dim3(64, SPLITS), 256, 0, stream>>>(z, e16, h, ps, pi, p2);
  k2_merge<<<64, 256, 0, stream>>>(ps, pi, p2, idxf, out_idx, list, cnt, acc);
  k_rescue<<<128, 512, 0, stream>>>(z, emb, h, list, cnt, idxf, out_idx);
  k3_quant<<<4096, 256, 0, stream>>>(z, emb, idxf, out, acc);
  k4_loss<<<1, 1, 0, stream>>>(acc, out_loss);
}

// Round 4
// 392.018 us; speedup vs baseline: 1.1439x; 1.1439x over previous
//
#include <hip/hip_runtime.h>

// VQ-VAE vector quantizer. Round 4.
// z: [16,64,32,32] f32, emb: [8192,64] f32. N=16384 pts, C=64, V=8192.
// out = [ z_q_st (1048576) | idx as f32 (16384) | vq_loss (1) ]
//
// R3 post-mortem: k_rescue was L1-transaction-bound (stride-256B lane reads =
// 64 lines/instr, every block swept all of emb) -> 231 us at 4% VALUBusy.
// R4: (a) rescue reads emb COALESCED (8 lanes per code, shfl-reduce);
//     (b) k1 drops LDS entirely: k_pre stores e16 pre-swizzled in B-fragment
//         order so B-frags are coalesced dwordx4 global loads (L1-resident
//         16KB/chunk). No barriers, no bank conflicts.

typedef _Float16 half8 __attribute__((ext_vector_type(8)));
typedef float f32x16 __attribute__((ext_vector_type(16)));

#define N_PTS 16384
#define SPLITS 8
#define THR 0.08f

// e16 swizzled layout, halfs: off(v,c) = (v>>5)*2048 + ((c>>4)*2+((c>>3)&1))*256
//                                        + (v&31)*8 + (c&7)

// ---------------- k_pre: emb -> swizzled fp16, half-norms, zero cnt ------------
__global__ __launch_bounds__(256) void k_pre(const float* __restrict__ emb,
                                             float* __restrict__ h,
                                             unsigned short* __restrict__ e16,
                                             int* __restrict__ cnt) {
  int v = blockIdx.x * 256 + threadIdx.x;   // grid 32 -> 8192
  const float4* e4 = (const float4*)(emb + v * 64);
  float s = 0.f;
  float row[64];
#pragma unroll
  for (int i = 0; i < 16; ++i) {
    float4 a = e4[i];
    row[i * 4 + 0] = a.x; row[i * 4 + 1] = a.y;
    row[i * 4 + 2] = a.z; row[i * 4 + 3] = a.w;
    s += a.x * a.x + a.y * a.y + a.z * a.z + a.w * a.w;
  }
  unsigned short* base = e16 + (v >> 5) * 2048 + (v & 31) * 8;
#pragma unroll
  for (int kc = 0; kc < 4; ++kc)
#pragma unroll
    for (int h5 = 0; h5 < 2; ++h5) {
      half8 o;
#pragma unroll
      for (int j = 0; j < 8; ++j) o[j] = (_Float16)row[kc * 16 + h5 * 8 + j];
      *(half8*)(base + (kc * 2 + h5) * 256) = o;
    }
  h[v] = 0.5f * s;
  if (v == 0) *cnt = 0;
}

// ---------------- k1: MFMA scores + per-split top-2 (no LDS) ----------------
// grid (64, 8). block 256 = 4 waves; wave owns 64 points (2 subtiles of 32),
// block owns 256 points and sweeps 1024 codes (8 chunks of 128 = 4 code-tiles).
__global__ __launch_bounds__(256, 2) void k1_score(
    const float* __restrict__ z, const unsigned short* __restrict__ e16,
    const float* __restrict__ h,
    float* __restrict__ ps, float* __restrict__ pi, float* __restrict__ p2) {
  const int tid = threadIdx.x;
  const int lane = tid & 63;
  const int wid = tid >> 6;
  const int h5 = lane >> 5;     // k-half
  const int c5 = lane & 31;     // col (code) / row (point) id within 32
  const int n0 = blockIdx.x * 256;
  const int split = blockIdx.y;

  const int b = n0 >> 10;
  const int hw0 = n0 & 1023;

  // A fragments: A[m=c5][k=h5*8+j], k = channel. Loaded once, fp32->fp16.
  half8 A[2][4];
  {
    const float* zb = z + b * 65536 + hw0 + wid * 64 + c5;
#pragma unroll
    for (int sub = 0; sub < 2; ++sub)
#pragma unroll
      for (int kc = 0; kc < 4; ++kc) {
        half8 a;
#pragma unroll
        for (int j = 0; j < 8; ++j)
          a[j] = (_Float16)zb[sub * 32 + (kc * 16 + h5 * 8 + j) * 1024];
        A[sub][kc] = a;
      }
  }

  float s1[2][16], i1[2][16], s2[2][16];
#pragma unroll
  for (int sub = 0; sub < 2; ++sub)
#pragma unroll
    for (int e = 0; e < 16; ++e) {
      s1[sub][e] = -3.0e38f; i1[sub][e] = 0.f; s2[sub][e] = -3.0e38f;
    }

  for (int ch = 0; ch < 8; ++ch) {
    const int vb = split * 1024 + ch * 128;
    const unsigned short* gbase = e16 + (vb >> 5) * 2048 + (h5 * 256 + c5 * 8);

#pragma unroll
    for (int t = 0; t < 4; ++t) {
      // B fragments: B[n=t*32+c5][k=kc*16+h5*8+j], coalesced dwordx4 loads
      half8 B[4];
#pragma unroll
      for (int kc = 0; kc < 4; ++kc)
        B[kc] = *(const half8*)(gbase + t * 2048 + kc * 512);
      const int rr = t * 32 + c5;
      const float hv = h[vb + rr];
      const float vf = (float)(vb + rr);
      const float nhv = -hv;

#pragma unroll
      for (int sub = 0; sub < 2; ++sub) {
        f32x16 acc;
#pragma unroll
        for (int e = 0; e < 16; ++e) acc[e] = nhv;
#pragma unroll
        for (int kc = 0; kc < 4; ++kc)
          acc = __builtin_amdgcn_mfma_f32_32x32x16_f16(A[sub][kc], B[kc], acc, 0, 0, 0);
#pragma unroll
        for (int e = 0; e < 16; ++e) {
          float sc = acc[e];
          float mn = fminf(sc, s1[sub][e]);
          bool gt = sc > s1[sub][e];
          s2[sub][e] = fmaxf(s2[sub][e], mn);
          i1[sub][e] = gt ? vf : i1[sub][e];
          s1[sub][e] = fmaxf(s1[sub][e], sc);
        }
      }
    }
  }

  // butterfly merge across the 32 col-lanes (near-ties resolved by rescue)
#pragma unroll
  for (int off = 16; off >= 1; off >>= 1) {
#pragma unroll
    for (int sub = 0; sub < 2; ++sub)
#pragma unroll
      for (int e = 0; e < 16; ++e) {
        float os = __shfl_xor(s1[sub][e], off);
        float oi = __shfl_xor(i1[sub][e], off);
        float o2 = __shfl_xor(s2[sub][e], off);
        float mn = fminf(s1[sub][e], os);
        s2[sub][e] = fmaxf(fmaxf(s2[sub][e], o2), mn);
        bool gt = os > s1[sub][e];
        i1[sub][e] = gt ? oi : i1[sub][e];
        s1[sub][e] = fmaxf(s1[sub][e], os);
      }
  }

  if (c5 == 0) {
#pragma unroll
    for (int sub = 0; sub < 2; ++sub)
#pragma unroll
      for (int e = 0; e < 16; ++e) {
        int n = n0 + wid * 64 + sub * 32 + (e & 3) + 8 * (e >> 2) + 4 * h5;
        int o = split * N_PTS + n;
        ps[o] = s1[sub][e]; pi[o] = i1[sub][e]; p2[o] = s2[sub][e];
      }
  }
}

// ---------------- k2: merge splits, margin test, emit idx, zero accs ----------
__global__ __launch_bounds__(256) void k2_merge(
    const float* __restrict__ ps, const float* __restrict__ pi,
    const float* __restrict__ p2,
    int* __restrict__ idxf, float* __restrict__ out_idx,
    int* __restrict__ list, int* __restrict__ cnt, float* __restrict__ acc,
    int* __restrict__ done) {
  int n = blockIdx.x * 256 + threadIdx.x;   // grid 64 -> 16384
  float S1 = ps[n], I1 = pi[n], S2 = p2[n];
#pragma unroll
  for (int s = 1; s < SPLITS; ++s) {
    int o = s * N_PTS + n;
    float a = ps[o], ai = pi[o], a2 = p2[o];
    if (a > S1) { S2 = fmaxf(fmaxf(S2, a2), S1); S1 = a; I1 = ai; }
    else        { S2 = fmaxf(S2, a); }
  }
  idxf[n] = (int)I1;
  out_idx[n] = I1;
  if (S1 - S2 < THR) {
    int p = atomicAdd(cnt, 1);
    list[p] = n;
  }
  if (n == 0) { *acc = 0.f; *done = 0; }
}

// ---------------- k_rescue: exact fp32, coalesced (8 lanes per code) ----------
__global__ __launch_bounds__(256) void k_rescue(
    const float* __restrict__ z, const float* __restrict__ emb,
    const float* __restrict__ h, const int* __restrict__ list,
    const int* __restrict__ cnt,
    int* __restrict__ idxf, float* __restrict__ out_idx) {
  __shared__ float rs[4], ri[4];
  const int tid = threadIdx.x;
  const int lane = tid & 63, wv = tid >> 6;
  const int sub = lane >> 3;       // code slot within wave round (0..7)
  const int cb = (lane & 7) * 8;   // this lane's 8 channels
  const int count = *cnt;

  for (int p = blockIdx.x; p < count; p += gridDim.x) {
    const int n = list[p];
    const int bb = n >> 10, hw = n & 1023;
    // this lane's 8 z-channels (channel stride 1024)
    float zr[8];
#pragma unroll
    for (int k = 0; k < 8; ++k) zr[k] = z[bb * 65536 + (cb + k) * 1024 + hw];

    float bs = -3.0e38f, bi = 0.f;
    for (int r = 0; r < 256; ++r) {
      const int cg = r * 32 + wv * 8 + sub;        // ascending per lane
      const float4* er = (const float4*)(emb + cg * 64 + cb);
      float4 a = er[0], c = er[1];
      float d = zr[0] * a.x;
      d = fmaf(zr[1], a.y, d); d = fmaf(zr[2], a.z, d); d = fmaf(zr[3], a.w, d);
      d = fmaf(zr[4], c.x, d); d = fmaf(zr[5], c.y, d);
      d = fmaf(zr[6], c.z, d); d = fmaf(zr[7], c.w, d);
      d += __shfl_xor(d, 1);
      d += __shfl_xor(d, 2);
      d += __shfl_xor(d, 4);
      float sc = d - h[cg];
      if (sc > bs) { bs = sc; bi = (float)cg; }    // strict >: first occurrence
    }
    // merge across lanes (groups hold duplicates; tie -> lower index)
#pragma unroll
    for (int off = 32; off >= 1; off >>= 1) {
      float os = __shfl_xor(bs, off);
      float oi = __shfl_xor(bi, off);
      if (os > bs || (os == bs && oi < bi)) { bs = os; bi = oi; }
    }
    if (lane == 0) { rs[wv] = bs; ri[wv] = bi; }
    __syncthreads();
    if (tid == 0) {
      float s = rs[0], i = ri[0];
#pragma unroll
      for (int w = 1; w < 4; ++w) {
        if (rs[w] > s || (rs[w] == s && ri[w] < i)) { s = rs[w]; i = ri[w]; }
      }
      idxf[n] = (int)i;
      out_idx[n] = i;
    }
    __syncthreads();
  }
}

// ---------------- k3: gather, straight-through out, loss (last block ends) ----
__global__ __launch_bounds__(256) void k3_quant(
    const float* __restrict__ z, const float* __restrict__ emb,
    const int* __restrict__ idxf,
    float* __restrict__ out, float* __restrict__ acc, int* __restrict__ done,
    float* __restrict__ out_loss) {
  int g = blockIdx.x * 256 + threadIdx.x;   // grid 4096 -> 1048576, [b][c][hw]
  int b = g >> 16;
  int c = (g >> 10) & 63;
  int hw = g & 1023;
  int n = (b << 10) | hw;
  float zv = z[g];
  float q = emb[idxf[n] * 64 + c];
  float d = q - zv;
  out[g] = zv + d;
  float val = d * d;
#pragma unroll
  for (int off = 32; off >= 1; off >>= 1) val += __shfl_down(val, off);
  __shared__ float wsum[4];
  int lane = threadIdx.x & 63, wv = threadIdx.x >> 6;
  if (lane == 0) wsum[wv] = val;
  __syncthreads();
  if (threadIdx.x == 0) {
    atomicAdd(acc, wsum[0] + wsum[1] + wsum[2] + wsum[3]);
    __threadfence();
    int old = atomicAdd(done, 1);
    if (old == 4095) {
      float total = atomicAdd(acc, 0.0f);
      out_loss[0] = 1.25f * total * (1.0f / 1048576.0f);
    }
  }
}

extern "C" void kernel_launch(void* const* d_in, const int* in_sizes, int n_in,
                              void* d_out, int out_size, void* d_ws, size_t ws_size,
                              hipStream_t stream) {
  const float* z   = (const float*)d_in[0];
  const float* emb = (const float*)d_in[1];
  float* out = (float*)d_out;
  float* ws  = (float*)d_ws;

  float* h   = ws;                                    // 8192
  unsigned short* e16 = (unsigned short*)(ws + 8192); // 524288 halfs
  float* ps  = ws + 8192 + 262144;                    // 8*16384
  float* pi  = ps + SPLITS * N_PTS;
  float* p2  = pi + SPLITS * N_PTS;
  int* idxf  = (int*)(p2 + SPLITS * N_PTS);           // 16384
  int* list  = idxf + N_PTS;                          // 16384
  int* cnt   = list + N_PTS;                          // 1
  float* acc = (float*)(cnt + 1);                     // 1
  int* done  = (int*)(acc + 1);                       // 1

  float* out_idx  = out + 1048576;
  float* out_loss = out + 1048576 + 16384;

  k_pre<<<32, 256, 0, stream>>>(emb, h, e16, cnt);
  k1_score<<<dim3(64, SPLITS), 256, 0, stream>>>(z, e16, h, ps, pi, p2);
  k2_merge<<<64, 256, 0, stream>>>(ps, pi, p2, idxf, out_idx, list, cnt, acc, done);
  k_rescue<<<512, 256, 0, stream>>>(z, emb, h, list, cnt, idxf, out_idx);
  k3_quant<<<4096, 256, 0, stream>>>(z, emb, idxf, out, acc, done, out_loss);
}

// Round 5
// 218.335 us; speedup vs baseline: 2.0538x; 1.7955x over previous
//
#include <hip/hip_runtime.h>

// VQ-VAE vector quantizer. Round 5.
// z: [16,64,32,32] f32, emb: [8192,64] f32. N=16384 pts, C=64, V=8192.
// out = [ z_q_st (1048576) | idx as f32 (16384) | vq_loss (1) ]
//
// R4 post-mortem: k1 spilled (top-2 state for 32x32 tile = ~190 VGPR >
// 128 cap -> 188MB scratch writes, 114us); k3 serialized on 8192
// single-line device atomics (115us at 1% VALU).
// R5: k1 -> mfma 16x16x32 (state 12 regs/lane, no spill, swizzled-coalesced
// B loads); k3 -> atomic-free two-stage reduction.

typedef _Float16 half8 __attribute__((ext_vector_type(8)));
typedef float f32x4 __attribute__((ext_vector_type(4)));

#define N_PTS 16384
#define SPLITS 4
#define THR 0.08f

// e16 swizzled (halfs): off(v,c) = (v>>4)*1024 + (c>>5)*512
//                                   + ((c>>3)&3)*128 + (v&15)*8 + (c&7)
// -> per-wave B-frag load (tile T, half H): e16 + T*1024 + H*512 + lane*8,
//    contiguous 1KB, giving B[n=lane&15][k=(lane>>4)*8+j].

// ---------------- k_pre: emb -> swizzled fp16, half-norms, zero cnt ----------
__global__ __launch_bounds__(256) void k_pre(const float* __restrict__ emb,
                                             float* __restrict__ h,
                                             unsigned short* __restrict__ e16,
                                             int* __restrict__ cnt) {
  int v = blockIdx.x * 256 + threadIdx.x;   // grid 32 -> 8192
  const float4* e4 = (const float4*)(emb + v * 64);
  float s = 0.f;
  float row[64];
#pragma unroll
  for (int i = 0; i < 16; ++i) {
    float4 a = e4[i];
    row[i * 4 + 0] = a.x; row[i * 4 + 1] = a.y;
    row[i * 4 + 2] = a.z; row[i * 4 + 3] = a.w;
    s += a.x * a.x + a.y * a.y + a.z * a.z + a.w * a.w;
  }
  unsigned short* base = e16 + (v >> 4) * 1024 + (v & 15) * 8;
#pragma unroll
  for (int c8 = 0; c8 < 8; ++c8) {
    half8 o;
#pragma unroll
    for (int j = 0; j < 8; ++j) o[j] = (_Float16)row[c8 * 8 + j];
    *(half8*)(base + (c8 >> 2) * 512 + (c8 & 3) * 128) = o;
  }
  h[v] = 0.5f * s;
  if (v == 0) *cnt = 0;
}

// ---------------- k1: 16x16x32 MFMA scores + per-split top-2 ----------------
// grid (256, 4). block 256 = 4 waves; wave owns 16 points, sweeps 2048 codes
// (128 tiles of 16). Per-lane state: 4 rows x (s1,i1,s2) = 12 regs.
__global__ __launch_bounds__(256, 4) void k1_score(
    const float* __restrict__ z, const unsigned short* __restrict__ e16,
    const float* __restrict__ h,
    float* __restrict__ ps, float* __restrict__ pi, float* __restrict__ p2) {
  const int tid = threadIdx.x;
  const int lane = tid & 63;
  const int wid = tid >> 6;
  const int cl = lane & 15;     // A row (point) / B col (code) within tile
  const int gq = lane >> 4;     // quad: selects k-slice / C rows
  const int n0 = blockIdx.x * 64 + wid * 16;
  const int split = blockIdx.y;

  const int b = n0 >> 10;
  const int hw0 = n0 & 1023;

  // A frags: A[m=cl][k=gq*8+j] (half H covers channels H*32..H*32+31)
  half8 A[2];
  {
    const float* zb = z + b * 65536 + hw0 + cl;
#pragma unroll
    for (int H = 0; H < 2; ++H) {
      half8 a;
#pragma unroll
      for (int j = 0; j < 8; ++j)
        a[j] = (_Float16)zb[(H * 32 + gq * 8 + j) * 1024];
      A[H] = a;
    }
  }

  float s1[4], i1f[4], s2[4];
#pragma unroll
  for (int r = 0; r < 4; ++r) { s1[r] = -3.0e38f; i1f[r] = 0.f; s2[r] = -3.0e38f; }

  const int vbase = split * 2048;
  const unsigned short* bbase = e16 + (vbase >> 4) * 1024 + lane * 8;

#pragma unroll 4
  for (int T = 0; T < 128; ++T) {
    const unsigned short* bp = bbase + T * 1024;
    half8 B0 = *(const half8*)bp;
    half8 B1 = *(const half8*)(bp + 512);
    const int code = vbase + T * 16 + cl;
    const float nhv = -h[code];
    const float vf = (float)code;

    f32x4 acc;
    acc[0] = nhv; acc[1] = nhv; acc[2] = nhv; acc[3] = nhv;
    acc = __builtin_amdgcn_mfma_f32_16x16x32_f16(A[0], B0, acc, 0, 0, 0);
    acc = __builtin_amdgcn_mfma_f32_16x16x32_f16(A[1], B1, acc, 0, 0, 0);

    // per-lane running top-2 for 4 rows (points), this lane's col (code)
#pragma unroll
    for (int r = 0; r < 4; ++r) {
      float sc = acc[r];
      s2[r] = fmaxf(fminf(sc, s1[r]), s2[r]);   // med3(top2 update)
      bool gt = sc > s1[r];                     // strict: first occurrence
      i1f[r] = gt ? vf : i1f[r];
      s1[r] = fmaxf(s1[r], sc);
    }
  }

  // butterfly merge across the 16 cols (lanes with same gq hold same rows)
#pragma unroll
  for (int off = 8; off >= 1; off >>= 1) {
#pragma unroll
    for (int r = 0; r < 4; ++r) {
      float os = __shfl_xor(s1[r], off);
      float oi = __shfl_xor(i1f[r], off);
      float o2 = __shfl_xor(s2[r], off);
      s2[r] = fmaxf(fmaxf(s2[r], o2), fminf(s1[r], os));
      bool gt = os > s1[r];     // exact ties -> margin 0 -> rescue resolves
      i1f[r] = gt ? oi : i1f[r];
      s1[r] = fmaxf(s1[r], os);
    }
  }

  if (cl == 0) {
#pragma unroll
    for (int r = 0; r < 4; ++r) {
      int n = n0 + gq * 4 + r;               // C row = gq*4 + reg
      int o = split * N_PTS + n;
      ps[o] = s1[r]; pi[o] = i1f[r]; p2[o] = s2[r];
    }
  }
}

// ---------------- k2: merge splits, margin test, emit idx ----------------
__global__ __launch_bounds__(256) void k2_merge(
    const float* __restrict__ ps, const float* __restrict__ pi,
    const float* __restrict__ p2,
    int* __restrict__ idxf, float* __restrict__ out_idx,
    int* __restrict__ list, int* __restrict__ cnt) {
  int n = blockIdx.x * 256 + threadIdx.x;   // grid 64 -> 16384
  float S1 = ps[n], I1 = pi[n], S2 = p2[n];
#pragma unroll
  for (int s = 1; s < SPLITS; ++s) {
    int o = s * N_PTS + n;
    float a = ps[o], ai = pi[o], a2 = p2[o];
    if (a > S1) { S2 = fmaxf(fmaxf(S2, a2), S1); S1 = a; I1 = ai; }
    else        { S2 = fmaxf(S2, a); }
  }
  idxf[n] = (int)I1;
  out_idx[n] = I1;
  if (S1 - S2 < THR) {
    int p = atomicAdd(cnt, 1);
    list[p] = n;
  }
}

// ---------------- k_rescue: exact fp32, coalesced (8 lanes per code) ----------
__global__ __launch_bounds__(256) void k_rescue(
    const float* __restrict__ z, const float* __restrict__ emb,
    const float* __restrict__ h, const int* __restrict__ list,
    const int* __restrict__ cnt,
    int* __restrict__ idxf, float* __restrict__ out_idx) {
  __shared__ float rs[4], ri[4];
  const int tid = threadIdx.x;
  const int lane = tid & 63, wv = tid >> 6;
  const int sub = lane >> 3;       // code slot within wave round (0..7)
  const int cb = (lane & 7) * 8;   // this lane's 8 channels
  const int count = *cnt;

  for (int p = blockIdx.x; p < count; p += gridDim.x) {
    const int n = list[p];
    const int bb = n >> 10, hw = n & 1023;
    float zr[8];
#pragma unroll
    for (int k = 0; k < 8; ++k) zr[k] = z[bb * 65536 + (cb + k) * 1024 + hw];

    float bs = -3.0e38f, bi = 0.f;
    for (int r = 0; r < 256; ++r) {
      const int cg = r * 32 + wv * 8 + sub;        // ascending per lane
      const float4* er = (const float4*)(emb + cg * 64 + cb);
      float4 a = er[0], c = er[1];
      float d = zr[0] * a.x;
      d = fmaf(zr[1], a.y, d); d = fmaf(zr[2], a.z, d); d = fmaf(zr[3], a.w, d);
      d = fmaf(zr[4], c.x, d); d = fmaf(zr[5], c.y, d);
      d = fmaf(zr[6], c.z, d); d = fmaf(zr[7], c.w, d);
      d += __shfl_xor(d, 1);
      d += __shfl_xor(d, 2);
      d += __shfl_xor(d, 4);
      float sc = d - h[cg];
      if (sc > bs) { bs = sc; bi = (float)cg; }    // strict >: first occurrence
    }
#pragma unroll
    for (int off = 32; off >= 1; off >>= 1) {
      float os = __shfl_xor(bs, off);
      float oi = __shfl_xor(bi, off);
      if (os > bs || (os == bs && oi < bi)) { bs = os; bi = oi; }
    }
    if (lane == 0) { rs[wv] = bs; ri[wv] = bi; }
    __syncthreads();
    if (tid == 0) {
      float s = rs[0], i = ri[0];
#pragma unroll
      for (int w = 1; w < 4; ++w) {
        if (rs[w] > s || (rs[w] == s && ri[w] < i)) { s = rs[w]; i = ri[w]; }
      }
      idxf[n] = (int)i;
      out_idx[n] = i;
    }
    __syncthreads();
  }
}

// ---------------- k3: gather, straight-through out, block partial loss --------
__global__ __launch_bounds__(256) void k3_quant(
    const float* __restrict__ z, const float* __restrict__ emb,
    const int* __restrict__ idxf,
    float* __restrict__ out, float* __restrict__ psum) {
  int t = blockIdx.x * 256 + threadIdx.x;   // grid 1024 -> 262144 float4 slots
  int g = t * 4;
  int b = g >> 16;
  int c = (g >> 10) & 63;
  int hw = g & 1023;
  int n = (b << 10) | hw;                   // n..n+3, 4-aligned
  float4 zv = *(const float4*)(z + g);
  int4 iv = *(const int4*)(idxf + n);
  float q0 = emb[iv.x * 64 + c];
  float q1 = emb[iv.y * 64 + c];
  float q2 = emb[iv.z * 64 + c];
  float q3 = emb[iv.w * 64 + c];
  float d0 = q0 - zv.x, d1 = q1 - zv.y, d2 = q2 - zv.z, d3 = q3 - zv.w;
  float4 o;
  o.x = zv.x + d0; o.y = zv.y + d1; o.z = zv.z + d2; o.w = zv.w + d3;
  *(float4*)(out + g) = o;
  float val = d0 * d0 + d1 * d1 + d2 * d2 + d3 * d3;
#pragma unroll
  for (int off = 32; off >= 1; off >>= 1) val += __shfl_down(val, off);
  __shared__ float wsum[4];
  int lane = threadIdx.x & 63, wv = threadIdx.x >> 6;
  if (lane == 0) wsum[wv] = val;
  __syncthreads();
  if (threadIdx.x == 0)
    psum[blockIdx.x] = wsum[0] + wsum[1] + wsum[2] + wsum[3];
}

// ---------------- k4: final loss reduce (1024 partials) ----------------
__global__ __launch_bounds__(256) void k4_loss(const float* __restrict__ psum,
                                               float* __restrict__ out_loss) {
  int tid = threadIdx.x;
  float val = psum[tid] + psum[tid + 256] + psum[tid + 512] + psum[tid + 768];
#pragma unroll
  for (int off = 32; off >= 1; off >>= 1) val += __shfl_down(val, off);
  __shared__ float wsum[4];
  int lane = tid & 63, wv = tid >> 6;
  if (lane == 0) wsum[wv] = val;
  __syncthreads();
  if (tid == 0)
    out_loss[0] = 1.25f * (wsum[0] + wsum[1] + wsum[2] + wsum[3]) * (1.0f / 1048576.0f);
}

extern "C" void kernel_launch(void* const* d_in, const int* in_sizes, int n_in,
                              void* d_out, int out_size, void* d_ws, size_t ws_size,
                              hipStream_t stream) {
  const float* z   = (const float*)d_in[0];
  const float* emb = (const float*)d_in[1];
  float* out = (float*)d_out;
  float* ws  = (float*)d_ws;

  float* h   = ws;                                    // 8192
  unsigned short* e16 = (unsigned short*)(ws + 8192); // 524288 halfs = 262144 f
  float* ps  = ws + 8192 + 262144;                    // 4*16384
  float* pi  = ps + SPLITS * N_PTS;                   // 4*16384
  float* p2  = pi + SPLITS * N_PTS;                   // 4*16384
  int* idxf  = (int*)(p2 + SPLITS * N_PTS);           // 16384
  int* list  = idxf + N_PTS;                          // 16384
  int* cnt   = list + N_PTS;                          // 1
  float* psum = (float*)(cnt + 1);                    // 1024

  float* out_idx  = out + 1048576;
  float* out_loss = out + 1048576 + 16384;

  k_pre<<<32, 256, 0, stream>>>(emb, h, e16, cnt);
  k1_score<<<dim3(256, SPLITS), 256, 0, stream>>>(z, e16, h, ps, pi, p2);
  k2_merge<<<64, 256, 0, stream>>>(ps, pi, p2, idxf, out_idx, list, cnt);
  k_rescue<<<512, 256, 0, stream>>>(z, emb, h, list, cnt, idxf, out_idx);
  k3_quant<<<1024, 256, 0, stream>>>(z, emb, idxf, out, psum);
  k4_loss<<<1, 256, 0, stream>>>(psum, out_loss);
}